// Round 3
// baseline (52499.664 us; speedup 1.0000x reference)
//
#include <hip/hip_runtime.h>
#include <math.h>

#define S_  256
#define B_  64
#define E_  512
#define H_  512
#define G4_ 2048   // 4*H
#define NL_ 4
#define E4_ 128    // H/4
#define NWG_ 256   // persistent grid (both directions)

__device__ __forceinline__ float fsigmoid(float x) {
    return 1.0f / (1.0f + __expf(-x));
}
__device__ __forceinline__ float ftanh_(float x) {
    x = fminf(fmaxf(x, -15.0f), 15.0f);
    float e = __expf(2.0f * x);
    return (e - 1.0f) / (e + 1.0f);
}

// ---------------------------------------------------------------------------
// A-tile loader: T4=0 -> row-major [M][E]; T4=1 -> [t][e/4][b][4] (hsum layout)
// ---------------------------------------------------------------------------
template<int T4>
__device__ __forceinline__ float4 ldA(const float* __restrict__ A, int m, int kk) {
    if constexpr (T4) {
        int t = m >> 6, b = m & 63;
        return *(const float4*)&A[(((size_t)t * E4_ + (kk >> 2)) * B_ + b) * 4];
    } else {
        return *(const float4*)&A[(size_t)m * E_ + kk];
    }
}

// pre[t][g][b] = sum_k In[t*64+b][k] * Wi[g][k] + bias[g]
#define BM_ 128
#define BN_ 128
#define BK_ 16

template<int T4>
__global__ __launch_bounds__(256) void pre_gemm_k(
    const float* __restrict__ In,
    const float* __restrict__ Wi,
    const float* __restrict__ bias,
    float* __restrict__ pre)
{
    __shared__ float As[BK_][BM_ + 4];
    __shared__ float Bs[BK_][BN_ + 4];

    const int tid = threadIdx.x;
    const int bx  = blockIdx.x;          // 0..2047
    const int m0  = (bx >> 4) * BM_;
    const int n0  = (bx & 15) * BN_;
    const int tx  = tid & 15;
    const int ty  = tid >> 4;
    const int lr  = tid >> 2;            // 0..63
    const int lc  = (tid & 3) << 2;      // 0,4,8,12

    float acc[8][8];
#pragma unroll
    for (int i = 0; i < 8; ++i)
#pragma unroll
        for (int j = 0; j < 8; ++j) acc[i][j] = 0.0f;

    for (int k0 = 0; k0 < E_; k0 += BK_) {
        float4 a0 = ldA<T4>(In, m0 + lr,      k0 + lc);
        float4 a1 = ldA<T4>(In, m0 + lr + 64, k0 + lc);
        float4 b0 = *(const float4*)&Wi[(size_t)(n0 + lr) * E_ + k0 + lc];
        float4 b1 = *(const float4*)&Wi[(size_t)(n0 + lr + 64) * E_ + k0 + lc];
        __syncthreads();
        As[lc + 0][lr] = a0.x; As[lc + 1][lr] = a0.y; As[lc + 2][lr] = a0.z; As[lc + 3][lr] = a0.w;
        As[lc + 0][lr + 64] = a1.x; As[lc + 1][lr + 64] = a1.y; As[lc + 2][lr + 64] = a1.z; As[lc + 3][lr + 64] = a1.w;
        Bs[lc + 0][lr] = b0.x; Bs[lc + 1][lr] = b0.y; Bs[lc + 2][lr] = b0.z; Bs[lc + 3][lr] = b0.w;
        Bs[lc + 0][lr + 64] = b1.x; Bs[lc + 1][lr + 64] = b1.y; Bs[lc + 2][lr + 64] = b1.z; Bs[lc + 3][lr + 64] = b1.w;
        __syncthreads();
#pragma unroll
        for (int kk = 0; kk < BK_; ++kk) {
            float4 av0 = *(const float4*)&As[kk][ty * 8];
            float4 av1 = *(const float4*)&As[kk][ty * 8 + 4];
            float4 bv0 = *(const float4*)&Bs[kk][tx * 8];
            float4 bv1 = *(const float4*)&Bs[kk][tx * 8 + 4];
            float a[8] = {av0.x, av0.y, av0.z, av0.w, av1.x, av1.y, av1.z, av1.w};
            float b[8] = {bv0.x, bv0.y, bv0.z, bv0.w, bv1.x, bv1.y, bv1.z, bv1.w};
#pragma unroll
            for (int i = 0; i < 8; ++i)
#pragma unroll
                for (int j = 0; j < 8; ++j)
                    acc[i][j] = fmaf(a[i], b[j], acc[i][j]);
        }
    }

#pragma unroll
    for (int i = 0; i < 8; ++i) {
        int m  = m0 + ty * 8 + i;
        int tt = m >> 6;
        int bb = m & 63;
#pragma unroll
        for (int j = 0; j < 8; ++j) {
            int n = n0 + tx * 8 + j;
            pre[((size_t)tt * G4_ + n) * B_ + bb] = acc[i][j] + bias[n];
        }
    }
}

// ---------------------------------------------------------------------------
// Persistent recurrence: whole layer, both directions, one launch.
// 256 WGs x 256 threads (all resident: 64K threads << 512K capacity).
// wg = (dir<<7)|jt; thread = (jl=tid>>6, b=tid&63); j = jt*4+jl.
// Per wall-step t: global barrier via cnt[t] (count to 256, relaxed spin +
// one acquire fence). fwd handles slot t, bwd slot 255-t (never equal), so
// hsum uses the race-free store(t<=127)/add(t>=128) protocol.
// h state ping-pongs in ping[dir][t&1]; c lives in registers.
// ---------------------------------------------------------------------------
__global__ __launch_bounds__(256) void lstm_persist_k(
    const float* __restrict__ pre,    // [S][G4][B]
    const float* __restrict__ Wh,     // [G4][H]
    float* __restrict__ hsum,         // [S][E4][B][4]  (T4 layout)
    float* __restrict__ ping,         // [2 dir][2 par][E4][B][4]
    unsigned* __restrict__ cnt)       // [S], zeroed before launch
{
    const int tid = threadIdx.x;
    const int dir = blockIdx.x >> 7;
    const int jt  = blockIdx.x & 127;
    const int b   = tid & 63;
    const int jl  = tid >> 6;
    const int j   = jt * 4 + jl;
    const int j_u = __builtin_amdgcn_readfirstlane(j);   // wave-uniform

    const float* w0 = Wh + (size_t)(0 * H_ + j_u) * H_;
    const float* w1 = Wh + (size_t)(1 * H_ + j_u) * H_;
    const float* w2 = Wh + (size_t)(2 * H_ + j_u) * H_;
    const float* w3 = Wh + (size_t)(3 * H_ + j_u) * H_;

    float c = 0.0f;

    for (int t = 0; t < S_; ++t) {
        const int tf = dir ? (S_ - 1 - t) : t;

        // pre is immutable during the layer: load before the barrier wait
        float z0 = pre[((size_t)tf * G4_ + j) * B_ + b];
        float z1 = pre[((size_t)tf * G4_ + (H_ + j)) * B_ + b];
        float z2 = pre[((size_t)tf * G4_ + (2 * H_ + j)) * B_ + b];
        float z3 = pre[((size_t)tf * G4_ + (3 * H_ + j)) * B_ + b];

        if (t > 0) {
            if (tid == 0) {
                int guard = 0;
                // relaxed spin: no per-poll cache invalidation
                while (__hip_atomic_load(&cnt[t - 1], __ATOMIC_RELAXED,
                                         __HIP_MEMORY_SCOPE_AGENT) < NWG_) {
                    if (++guard > (1 << 16)) break;   // safety net: fail, don't hang
                }
            }
            __syncthreads();
            __builtin_amdgcn_fence(__ATOMIC_ACQUIRE, "agent");   // one L1/L2 inv per step

            const float4* h4 = (const float4*)(ping +
                (size_t)(dir * 2 + ((t - 1) & 1)) * (E4_ * B_ * 4));
#pragma unroll 4
            for (int k4 = 0; k4 < E4_; ++k4) {
                float4 hv = h4[(size_t)k4 * B_ + b];
                float4 a0 = *(const float4*)(w0 + k4 * 4);
                float4 a1 = *(const float4*)(w1 + k4 * 4);
                float4 a2 = *(const float4*)(w2 + k4 * 4);
                float4 a3 = *(const float4*)(w3 + k4 * 4);
                z0 = fmaf(hv.x, a0.x, z0); z0 = fmaf(hv.y, a0.y, z0);
                z0 = fmaf(hv.z, a0.z, z0); z0 = fmaf(hv.w, a0.w, z0);
                z1 = fmaf(hv.x, a1.x, z1); z1 = fmaf(hv.y, a1.y, z1);
                z1 = fmaf(hv.z, a1.z, z1); z1 = fmaf(hv.w, a1.w, z1);
                z2 = fmaf(hv.x, a2.x, z2); z2 = fmaf(hv.y, a2.y, z2);
                z2 = fmaf(hv.z, a2.z, z2); z2 = fmaf(hv.w, a2.w, z2);
                z3 = fmaf(hv.x, a3.x, z3); z3 = fmaf(hv.y, a3.y, z3);
                z3 = fmaf(hv.z, a3.z, z3); z3 = fmaf(hv.w, a3.w, z3);
            }
        }

        // gate order: i, f, o, g
        float si = fsigmoid(z0);
        float sf = fsigmoid(z1);
        float so = fsigmoid(z2);
        float tg = ftanh_(z3);
        c = fmaf(sf, c, si * tg);
        float h = so * ftanh_(c);

        // next-step input (own direction, parity t&1)
        ping[((size_t)(dir * 2 + (t & 1)) * E4_ + (j >> 2)) * (B_ * 4) + b * 4 + (j & 3)] = h;

        // direction-sum output: globally barrier-ordered writers per slot
        size_t oidx = ((size_t)tf * E4_ + (j >> 2)) * (B_ * 4) + b * 4 + (j & 3);
        if (t <= 127) hsum[oidx] = h;
        else          hsum[oidx] += h;

        __builtin_amdgcn_fence(__ATOMIC_RELEASE, "agent");   // push stores to LLC
        __syncthreads();
        if (tid == 0)
            __hip_atomic_fetch_add(&cnt[t], 1u, __ATOMIC_RELAXED,
                                   __HIP_MEMORY_SCOPE_AGENT);
    }
}

// hsum (T4) -> out row-major [t][b][e]
__global__ __launch_bounds__(256) void t4_to_row_k(
    const float* __restrict__ hsum, float* __restrict__ out)
{
    int i  = blockIdx.x * 256 + threadIdx.x;   // 2,097,152 float4 units
    int e4 = i & (E4_ - 1);
    int b  = (i >> 7) & 63;
    int t  = i >> 13;
    float4 v = ((const float4*)hsum)[((size_t)t * E4_ + e4) * B_ + b];
    *(float4*)&out[((size_t)(t * B_ + b)) * E_ + e4 * 4] = v;
}

// out tail [b][h] = hf_final + hb_final (both at ping parity 1 after t=255)
__global__ __launch_bounds__(256) void tail_k(
    const float* __restrict__ pF, const float* __restrict__ pB,
    float* __restrict__ out2)
{
    int i = blockIdx.x * 256 + threadIdx.x;   // 32768
    int b = i >> 9, j = i & 511;
    size_t idx = ((size_t)(j >> 2) * B_ + b) * 4 + (j & 3);
    out2[i] = pF[idx] + pB[idx];
}

// ---------------------------------------------------------------------------
// Workspace (floats):
//   pre  : 33,554,432  (128 MB)
//   hsum :  8,388,608  ( 32 MB)
//   ping :    262,144  (  1 MB)
//   cnt  : 256 u32
// total ~161 MB
// ---------------------------------------------------------------------------
extern "C" void kernel_launch(void* const* d_in, const int* in_sizes, int n_in,
                              void* d_out, int out_size, void* d_ws, size_t ws_size,
                              hipStream_t stream) {
    const float* x    = (const float*)d_in[0];
    const float* Wi   = (const float*)d_in[1];
    const float* Wh   = (const float*)d_in[2];
    const float* bias = (const float*)d_in[3];
    float* out = (float*)d_out;

    float* ws   = (float*)d_ws;
    float* pre  = ws;
    float* hsum = pre  + (size_t)S_ * G4_ * B_;
    float* ping = hsum + (size_t)S_ * B_ * H_;
    unsigned* cnt = (unsigned*)(ping + (size_t)4 * E4_ * B_ * 4);

    for (int l = 0; l < NL_; ++l) {
        const float* wi_l = Wi + (size_t)l * G4_ * E_;
        const float* wh_l = Wh + (size_t)l * G4_ * H_;
        const float* b_l  = bias + (size_t)l * G4_;
        if (l == 0) pre_gemm_k<0><<<2048, 256, 0, stream>>>(x,    wi_l, b_l, pre);
        else        pre_gemm_k<1><<<2048, 256, 0, stream>>>(hsum, wi_l, b_l, pre);
        hipMemsetAsync(cnt, 0, S_ * sizeof(unsigned), stream);
        lstm_persist_k<<<NWG_, 256, 0, stream>>>(pre, wh_l, hsum, ping, cnt);
    }
    t4_to_row_k<<<8192, 256, 0, stream>>>(hsum, out);
    tail_k<<<128, 256, 0, stream>>>(ping + (size_t)1 * E4_ * B_ * 4,
                                    ping + (size_t)3 * E4_ * B_ * 4,
                                    out + (size_t)S_ * B_ * H_);
}

// Round 4
// 26017.932 us; speedup vs baseline: 2.0178x; 2.0178x over previous
//
#include <hip/hip_runtime.h>
#include <math.h>

#define S_  256
#define B_  64
#define E_  512
#define H_  512
#define G4_ 2048   // 4*H
#define NL_ 4
#define E4_ 128    // H/4
#define NWGD_ 128  // WGs per direction barrier domain

__device__ __forceinline__ float fsigmoid(float x) {
    return 1.0f / (1.0f + __expf(-x));
}
__device__ __forceinline__ float ftanh_(float x) {
    x = fminf(fmaxf(x, -15.0f), 15.0f);
    float e = __expf(2.0f * x);
    return (e - 1.0f) / (e + 1.0f);
}

// ---------------------------------------------------------------------------
// A-tile loader: T4=0 -> row-major [M][E] single input;
//                T4=1 -> T4 layout [t][e4][b][4], DUAL input summed (hsF+hsB)
// ---------------------------------------------------------------------------
template<int T4>
__device__ __forceinline__ float4 ldA(const float* __restrict__ A,
                                      const float* __restrict__ A2,
                                      int m, int kk) {
    if constexpr (T4) {
        int t = m >> 6, b = m & 63;
        size_t idx = (((size_t)t * E4_ + (kk >> 2)) * B_ + b) * 4;
        float4 u = *(const float4*)&A[idx];
        float4 v = *(const float4*)&A2[idx];
        return make_float4(u.x + v.x, u.y + v.y, u.z + v.z, u.w + v.w);
    } else {
        return *(const float4*)&A[(size_t)m * E_ + kk];
    }
}

// pre[t][g][b] = sum_k In[t*64+b][k] * Wi[g][k] + bias[g]
#define BM_ 128
#define BN_ 128
#define BK_ 16

template<int T4>
__global__ __launch_bounds__(256) void pre_gemm_k(
    const float* __restrict__ In,
    const float* __restrict__ In2,
    const float* __restrict__ Wi,
    const float* __restrict__ bias,
    float* __restrict__ pre)
{
    __shared__ float As[BK_][BM_ + 4];
    __shared__ float Bs[BK_][BN_ + 4];

    const int tid = threadIdx.x;
    const int bx  = blockIdx.x;          // 0..2047
    const int m0  = (bx >> 4) * BM_;
    const int n0  = (bx & 15) * BN_;
    const int tx  = tid & 15;
    const int ty  = tid >> 4;
    const int lr  = tid >> 2;            // 0..63
    const int lc  = (tid & 3) << 2;      // 0,4,8,12

    float acc[8][8];
#pragma unroll
    for (int i = 0; i < 8; ++i)
#pragma unroll
        for (int j = 0; j < 8; ++j) acc[i][j] = 0.0f;

    for (int k0 = 0; k0 < E_; k0 += BK_) {
        float4 a0 = ldA<T4>(In, In2, m0 + lr,      k0 + lc);
        float4 a1 = ldA<T4>(In, In2, m0 + lr + 64, k0 + lc);
        float4 b0 = *(const float4*)&Wi[(size_t)(n0 + lr) * E_ + k0 + lc];
        float4 b1 = *(const float4*)&Wi[(size_t)(n0 + lr + 64) * E_ + k0 + lc];
        __syncthreads();
        As[lc + 0][lr] = a0.x; As[lc + 1][lr] = a0.y; As[lc + 2][lr] = a0.z; As[lc + 3][lr] = a0.w;
        As[lc + 0][lr + 64] = a1.x; As[lc + 1][lr + 64] = a1.y; As[lc + 2][lr + 64] = a1.z; As[lc + 3][lr + 64] = a1.w;
        Bs[lc + 0][lr] = b0.x; Bs[lc + 1][lr] = b0.y; Bs[lc + 2][lr] = b0.z; Bs[lc + 3][lr] = b0.w;
        Bs[lc + 0][lr + 64] = b1.x; Bs[lc + 1][lr + 64] = b1.y; Bs[lc + 2][lr + 64] = b1.z; Bs[lc + 3][lr + 64] = b1.w;
        __syncthreads();
#pragma unroll
        for (int kk = 0; kk < BK_; ++kk) {
            float4 av0 = *(const float4*)&As[kk][ty * 8];
            float4 av1 = *(const float4*)&As[kk][ty * 8 + 4];
            float4 bv0 = *(const float4*)&Bs[kk][tx * 8];
            float4 bv1 = *(const float4*)&Bs[kk][tx * 8 + 4];
            float a[8] = {av0.x, av0.y, av0.z, av0.w, av1.x, av1.y, av1.z, av1.w};
            float b[8] = {bv0.x, bv0.y, bv0.z, bv0.w, bv1.x, bv1.y, bv1.z, bv1.w};
#pragma unroll
            for (int i = 0; i < 8; ++i)
#pragma unroll
                for (int j = 0; j < 8; ++j)
                    acc[i][j] = fmaf(a[i], b[j], acc[i][j]);
        }
    }

#pragma unroll
    for (int i = 0; i < 8; ++i) {
        int m  = m0 + ty * 8 + i;
        int tt = m >> 6;
        int bb = m & 63;
#pragma unroll
        for (int j = 0; j < 8; ++j) {
            int n = n0 + tx * 8 + j;
            pre[((size_t)tt * G4_ + n) * B_ + bb] = acc[i][j] + bias[n];
        }
    }
}

// ---------------------------------------------------------------------------
// Persistent recurrence, fence-free.
// 256 WGs x 256 threads (1/CU). wg = (dir<<7)|jt; waves w=0..3 split K into
// quarters; all waves compute partials for the WG's 4 j-columns; 16KB LDS
// reduce; wave w owns gate phase for j = jt*4 + w (c stays in a register).
// h published into per-direction, per-timestep history (hs[tf]) — every
// address written ONCE per kernel => consumer L2 never stale => normal cached
// reads. Publication via relaxed AGENT atomic store (write-through to LLC),
// drained by __syncthreads' vmcnt(0) before the relaxed counter add.
// Consumers poll cnt with relaxed AGENT loads. NO acquire/release fences.
// ---------------------------------------------------------------------------
__global__ __launch_bounds__(256) void lstm_persist_k(
    const float* __restrict__ pre,    // [S][G4][B]
    const float* __restrict__ Wh,     // [G4][H]
    float* __restrict__ hsF,          // [S][E4][B][4]
    float* __restrict__ hsB,          // [S][E4][B][4]
    unsigned* __restrict__ cnt)       // [2][S], zeroed before launch
{
    __shared__ float zp[4][4][4][B_];   // [wave][jj][gate][b] = 16 KB

    const int tid = threadIdx.x;
    const int dir = blockIdx.x >> 7;
    const int jt  = blockIdx.x & 127;
    const int b   = tid & 63;
    const int w_u = __builtin_amdgcn_readfirstlane(tid >> 6);  // wave id, uniform
    const int j0  = jt * 4;
    const int jown = j0 + w_u;

    float* hs = dir ? hsB : hsF;
    unsigned* mycnt = cnt + dir * S_;

    float c = 0.0f;

    for (int t = 0; t < S_; ++t) {
        const int tf = dir ? (S_ - 1 - t) : t;

        // own-j pre loads issued before the barrier wait (pre is immutable)
        float p0 = pre[((size_t)tf * G4_ + (0 * H_ + jown)) * B_ + b];
        float p1 = pre[((size_t)tf * G4_ + (1 * H_ + jown)) * B_ + b];
        float p2 = pre[((size_t)tf * G4_ + (2 * H_ + jown)) * B_ + b];
        float p3 = pre[((size_t)tf * G4_ + (3 * H_ + jown)) * B_ + b];

        float z[4][4];
#pragma unroll
        for (int jj = 0; jj < 4; ++jj)
#pragma unroll
            for (int g = 0; g < 4; ++g) z[jj][g] = 0.0f;

        if (t > 0) {
            if (tid == 0) {
                unsigned guard = 0;
                while (__hip_atomic_load(&mycnt[t - 1], __ATOMIC_RELAXED,
                                         __HIP_MEMORY_SCOPE_AGENT) < NWGD_) {
                    if (++guard > (1u << 16)) break;   // fail visibly, don't hang
                }
            }
            __syncthreads();

            const int ptf = dir ? (tf + 1) : (tf - 1);   // tf of previous wall step
            const float4* h4 = (const float4*)hs + (size_t)ptf * (E4_ * B_);

            // this wave's K-quarter: k4 in [w_u*32, w_u*32+32)
#pragma unroll 2
            for (int kk = 0; kk < 32; ++kk) {
                const int k4 = (w_u << 5) + kk;
                float4 hv = h4[(size_t)k4 * B_ + b];     // coalesced, cached (first touch)
#pragma unroll
                for (int g = 0; g < 4; ++g) {
#pragma unroll
                    for (int jj = 0; jj < 4; ++jj) {
                        // uniform address -> scalar load, stays hot in L2
                        const float4 wv = *(const float4*)(
                            Wh + ((size_t)g * H_ + j0 + jj) * H_ + (k4 << 2));
                        z[jj][g] = fmaf(hv.x, wv.x, z[jj][g]);
                        z[jj][g] = fmaf(hv.y, wv.y, z[jj][g]);
                        z[jj][g] = fmaf(hv.z, wv.z, z[jj][g]);
                        z[jj][g] = fmaf(hv.w, wv.w, z[jj][g]);
                    }
                }
            }
        }

        // cross-wave K reduction through LDS
#pragma unroll
        for (int jj = 0; jj < 4; ++jj)
#pragma unroll
            for (int g = 0; g < 4; ++g) zp[w_u][jj][g][b] = z[jj][g];
        __syncthreads();

        float zi = p0, zf = p1, zo = p2, zg = p3;
#pragma unroll
        for (int w2 = 0; w2 < 4; ++w2) {
            zi += zp[w2][w_u][0][b];
            zf += zp[w2][w_u][1][b];
            zo += zp[w2][w_u][2][b];
            zg += zp[w2][w_u][3][b];
        }

        // gate order: i, f, o, g
        float si = fsigmoid(zi);
        float sf = fsigmoid(zf);
        float so = fsigmoid(zo);
        float tg = ftanh_(zg);
        c = fmaf(sf, c, si * tg);
        float h = so * ftanh_(c);

        // publish h: write-through to coherence point (no dirty L2 copy)
        __hip_atomic_store(&hs[(((size_t)tf * E4_ + jt) * B_ + b) * 4 + w_u], h,
                           __ATOMIC_RELAXED, __HIP_MEMORY_SCOPE_AGENT);

        // drains vmcnt(0) (store acked at LLC) and guards zp reuse
        __syncthreads();
        if (tid == 0)
            __hip_atomic_fetch_add(&mycnt[t], 1u, __ATOMIC_RELAXED,
                                   __HIP_MEMORY_SCOPE_AGENT);
    }
}

// out[t][b][e] = hsF[t][e4][b][.] + hsB[t][e4][b][.]
__global__ __launch_bounds__(256) void t4_to_row_k(
    const float* __restrict__ hsF, const float* __restrict__ hsB,
    float* __restrict__ out)
{
    int i  = blockIdx.x * 256 + threadIdx.x;   // 2,097,152 float4 units
    int e4 = i & (E4_ - 1);
    int b  = (i >> 7) & 63;
    int t  = i >> 13;
    size_t idx = ((size_t)t * E4_ + e4) * B_ + b;
    float4 u = ((const float4*)hsF)[idx];
    float4 v = ((const float4*)hsB)[idx];
    *(float4*)&out[((size_t)(t * B_ + b)) * E_ + e4 * 4] =
        make_float4(u.x + v.x, u.y + v.y, u.z + v.z, u.w + v.w);
}

// tail [b][j] = h_fwd(tf=255) + h_bwd(tf=0)
__global__ __launch_bounds__(256) void tail_k(
    const float* __restrict__ hsF, const float* __restrict__ hsB,
    float* __restrict__ out2)
{
    int i = blockIdx.x * 256 + threadIdx.x;   // 32768
    int b = i >> 9, j = i & 511;
    size_t f = (((size_t)255 * E4_ + (j >> 2)) * B_ + b) * 4 + (j & 3);
    size_t g = (((size_t)0   * E4_ + (j >> 2)) * B_ + b) * 4 + (j & 3);
    out2[i] = hsF[f] + hsB[g];
}

// ---------------------------------------------------------------------------
// Workspace (floats):
//   pre : 33,554,432   hsF : 8,388,608   hsB : 8,388,608   cnt : 512 u32
// total 192.0 MiB (< round-1's proven 193.5 MiB)
// ---------------------------------------------------------------------------
extern "C" void kernel_launch(void* const* d_in, const int* in_sizes, int n_in,
                              void* d_out, int out_size, void* d_ws, size_t ws_size,
                              hipStream_t stream) {
    const float* x    = (const float*)d_in[0];
    const float* Wi   = (const float*)d_in[1];
    const float* Wh   = (const float*)d_in[2];
    const float* bias = (const float*)d_in[3];
    float* out = (float*)d_out;

    float* ws  = (float*)d_ws;
    float* pre = ws;
    float* hsF = pre + (size_t)S_ * G4_ * B_;
    float* hsB = hsF + (size_t)S_ * B_ * H_;
    unsigned* cnt = (unsigned*)(hsB + (size_t)S_ * B_ * H_);

    for (int l = 0; l < NL_; ++l) {
        const float* wi_l = Wi + (size_t)l * G4_ * E_;
        const float* wh_l = Wh + (size_t)l * G4_ * H_;
        const float* b_l  = bias + (size_t)l * G4_;
        if (l == 0) pre_gemm_k<0><<<2048, 256, 0, stream>>>(x,   x,   wi_l, b_l, pre);
        else        pre_gemm_k<1><<<2048, 256, 0, stream>>>(hsF, hsB, wi_l, b_l, pre);
        hipMemsetAsync(cnt, 0, 2 * S_ * sizeof(unsigned), stream);
        lstm_persist_k<<<256, 256, 0, stream>>>(pre, wh_l, hsF, hsB, cnt);
    }
    t4_to_row_k<<<8192, 256, 0, stream>>>(hsF, hsB, out);
    tail_k<<<128, 256, 0, stream>>>(hsF, hsB, out + (size_t)S_ * B_ * H_);
}

// Round 5
// 16122.429 us; speedup vs baseline: 3.2563x; 1.6138x over previous
//
#include <hip/hip_runtime.h>
#include <math.h>

#define S_  256
#define B_  64
#define E_  512
#define H_  512
#define G4_ 2048   // 4*H
#define NL_ 4
#define E4_ 128    // H/4
#define NWGD_ 256  // WGs per direction barrier domain
#define NBANK_ 16  // barrier counter banks (separate cachelines)

__device__ __forceinline__ float fsigmoid(float x) {
    return 1.0f / (1.0f + __expf(-x));
}
__device__ __forceinline__ float ftanh_(float x) {
    x = fminf(fmaxf(x, -15.0f), 15.0f);
    float e = __expf(2.0f * x);
    return (e - 1.0f) / (e + 1.0f);
}

// ---------------------------------------------------------------------------
// A-tile loader: T4=0 -> row-major [M][E]; T4=1 -> [t][e4][b][4] dual (hsF+hsB)
// ---------------------------------------------------------------------------
template<int T4>
__device__ __forceinline__ float4 ldA(const float* __restrict__ A,
                                      const float* __restrict__ A2,
                                      int m, int kk) {
    if constexpr (T4) {
        int t = m >> 6, b = m & 63;
        size_t idx = (((size_t)t * E4_ + (kk >> 2)) * B_ + b) * 4;
        float4 u = *(const float4*)&A[idx];
        float4 v = *(const float4*)&A2[idx];
        return make_float4(u.x + v.x, u.y + v.y, u.z + v.z, u.w + v.w);
    } else {
        return *(const float4*)&A[(size_t)m * E_ + kk];
    }
}

// pre[t][g][b] = sum_k In[t*64+b][k] * Wi[g][k] + bias[g]
#define BM_ 128
#define BN_ 128
#define BK_ 16

template<int T4>
__global__ __launch_bounds__(256) void pre_gemm_k(
    const float* __restrict__ In,
    const float* __restrict__ In2,
    const float* __restrict__ Wi,
    const float* __restrict__ bias,
    float* __restrict__ pre)
{
    __shared__ float As[BK_][BM_ + 4];
    __shared__ float Bs[BK_][BN_ + 4];

    const int tid = threadIdx.x;
    const int bx  = blockIdx.x;          // 0..2047
    const int m0  = (bx >> 4) * BM_;
    const int n0  = (bx & 15) * BN_;
    const int tx  = tid & 15;
    const int ty  = tid >> 4;
    const int lr  = tid >> 2;            // 0..63
    const int lc  = (tid & 3) << 2;      // 0,4,8,12

    float acc[8][8];
#pragma unroll
    for (int i = 0; i < 8; ++i)
#pragma unroll
        for (int j = 0; j < 8; ++j) acc[i][j] = 0.0f;

    for (int k0 = 0; k0 < E_; k0 += BK_) {
        float4 a0 = ldA<T4>(In, In2, m0 + lr,      k0 + lc);
        float4 a1 = ldA<T4>(In, In2, m0 + lr + 64, k0 + lc);
        float4 b0 = *(const float4*)&Wi[(size_t)(n0 + lr) * E_ + k0 + lc];
        float4 b1 = *(const float4*)&Wi[(size_t)(n0 + lr + 64) * E_ + k0 + lc];
        __syncthreads();
        As[lc + 0][lr] = a0.x; As[lc + 1][lr] = a0.y; As[lc + 2][lr] = a0.z; As[lc + 3][lr] = a0.w;
        As[lc + 0][lr + 64] = a1.x; As[lc + 1][lr + 64] = a1.y; As[lc + 2][lr + 64] = a1.z; As[lc + 3][lr + 64] = a1.w;
        Bs[lc + 0][lr] = b0.x; Bs[lc + 1][lr] = b0.y; Bs[lc + 2][lr] = b0.z; Bs[lc + 3][lr] = b0.w;
        Bs[lc + 0][lr + 64] = b1.x; Bs[lc + 1][lr + 64] = b1.y; Bs[lc + 2][lr + 64] = b1.z; Bs[lc + 3][lr + 64] = b1.w;
        __syncthreads();
#pragma unroll
        for (int kk = 0; kk < BK_; ++kk) {
            float4 av0 = *(const float4*)&As[kk][ty * 8];
            float4 av1 = *(const float4*)&As[kk][ty * 8 + 4];
            float4 bv0 = *(const float4*)&Bs[kk][tx * 8];
            float4 bv1 = *(const float4*)&Bs[kk][tx * 8 + 4];
            float a[8] = {av0.x, av0.y, av0.z, av0.w, av1.x, av1.y, av1.z, av1.w};
            float b[8] = {bv0.x, bv0.y, bv0.z, bv0.w, bv1.x, bv1.y, bv1.z, bv1.w};
#pragma unroll
            for (int i = 0; i < 8; ++i)
#pragma unroll
                for (int j = 0; j < 8; ++j)
                    acc[i][j] = fmaf(a[i], b[j], acc[i][j]);
        }
    }

#pragma unroll
    for (int i = 0; i < 8; ++i) {
        int m  = m0 + ty * 8 + i;
        int tt = m >> 6;
        int bb = m & 63;
#pragma unroll
        for (int j = 0; j < 8; ++j) {
            int n = n0 + tx * 8 + j;
            pre[((size_t)tt * G4_ + n) * B_ + bb] = acc[i][j] + bias[n];
        }
    }
}

// ---------------------------------------------------------------------------
// Persistent recurrence v3: fence-free, 4 waves/SIMD for latency hiding.
// Grid 512 WGs x 512 threads (2 WGs/CU, 16 waves/CU). wg = (dir<<8)|rwg;
// WG owns j columns {2*rwg, 2*rwg+1}. Wave w = K-eighth kq (64 k values);
// each wave computes partials for all 8 (gate,jj) rows over its K range:
//   per step/wave: 128 s_load_dwordx4 (2 KB weights, K$-hot) + 16 coalesced
//   h float4 loads + 512 FMAs. Cross-wave reduce via 16 KB LDS.
// Threads 0..127 own (jj,b): hold c in a register, apply gates, publish h
// (write-through relaxed AGENT store, explicit vmcnt(0) drain).
// Barrier: 16-bank counter (bank = wg&15, 16 arrivals each, separate lines);
// poller sums 16 relaxed loads. Same proven first-touch h-history scheme.
// ---------------------------------------------------------------------------
__global__ __launch_bounds__(512) void lstm_persist_k(
    const float* __restrict__ pre,    // [S][G4][B]
    const float* __restrict__ Wh,     // [G4][H]
    float* __restrict__ hsF,          // [S][E4][B][4]
    float* __restrict__ hsB,          // [S][E4][B][4]
    unsigned* __restrict__ cnt)       // [2][S][NBANK][16], zeroed before launch
{
    __shared__ float zp[8][4][2][B_];   // [kq][gate][jj][b] = 16 KB

    const int tid = threadIdx.x;
    const int dir = blockIdx.x >> 8;
    const int rwg = blockIdx.x & 255;
    const int b   = tid & 63;
    const int kq  = __builtin_amdgcn_readfirstlane(tid >> 6);  // 0..7, uniform
    const int j0  = rwg * 2;

    float* hs = dir ? hsB : hsF;
    unsigned* mycnt = cnt + (size_t)dir * S_ * NBANK_ * 16;
    const int mybank = (rwg & (NBANK_ - 1)) * 16;

    // reducer role (threads 0..127 = waves 0,1): owns (rjj, b)
    const int rjj = (tid >> 6) & 1;
    const int rj  = j0 + rjj;

    // wave-uniform weight row bases for the 8 (gate,jj) rows
    const float* wrow[4][2];
#pragma unroll
    for (int g = 0; g < 4; ++g)
#pragma unroll
        for (int jj = 0; jj < 2; ++jj)
            wrow[g][jj] = Wh + ((size_t)g * H_ + j0 + jj) * H_;

    float c = 0.0f;

    for (int t = 0; t < S_; ++t) {
        const int tf = dir ? (S_ - 1 - t) : t;

        // reducer pre-loads issued before the barrier wait (pre immutable)
        float p[4];
        if (tid < 128) {
#pragma unroll
            for (int g = 0; g < 4; ++g)
                p[g] = pre[((size_t)tf * G4_ + g * H_ + rj) * B_ + b];
        }

        float z[4][2];
#pragma unroll
        for (int g = 0; g < 4; ++g)
#pragma unroll
            for (int jj = 0; jj < 2; ++jj) z[g][jj] = 0.0f;

        if (t > 0) {
            if (tid == 0) {
                const unsigned* cb = &mycnt[(size_t)(t - 1) * NBANK_ * 16];
                unsigned guard = 0;
                for (;;) {
                    unsigned s = 0;
#pragma unroll
                    for (int i = 0; i < NBANK_; ++i)
                        s += __hip_atomic_load(&cb[i * 16], __ATOMIC_RELAXED,
                                               __HIP_MEMORY_SCOPE_AGENT);
                    if (s >= NWGD_) break;
                    if (++guard > (1u << 16)) break;   // fail visibly, don't hang
                }
            }
            __syncthreads();

            const int ptf = dir ? (tf + 1) : (tf - 1);
            const float4* h4 = (const float4*)hs + (size_t)ptf * (E4_ * B_)
                               + (size_t)(kq * 16) * B_ + b;
#pragma unroll 4
            for (int kk = 0; kk < 16; ++kk) {
                float4 hv = h4[(size_t)kk * B_];      // coalesced, first-touch cached
                const int ko = kq * 64 + kk * 4;
#pragma unroll
                for (int g = 0; g < 4; ++g) {
#pragma unroll
                    for (int jj = 0; jj < 2; ++jj) {
                        const float4 wv = *(const float4*)(wrow[g][jj] + ko);  // s_load
                        z[g][jj] = fmaf(hv.x, wv.x, z[g][jj]);
                        z[g][jj] = fmaf(hv.y, wv.y, z[g][jj]);
                        z[g][jj] = fmaf(hv.z, wv.z, z[g][jj]);
                        z[g][jj] = fmaf(hv.w, wv.w, z[g][jj]);
                    }
                }
            }
        }

        // cross-wave K reduction
#pragma unroll
        for (int g = 0; g < 4; ++g)
#pragma unroll
            for (int jj = 0; jj < 2; ++jj) zp[kq][g][jj][b] = z[g][jj];
        __syncthreads();

        if (tid < 128) {
            float zg[4];
#pragma unroll
            for (int g = 0; g < 4; ++g) {
                float s = p[g];
#pragma unroll
                for (int q = 0; q < 8; ++q) s += zp[q][g][rjj][b];
                zg[g] = s;
            }
            // gate order: i, f, o, g
            float si = fsigmoid(zg[0]);
            float sf = fsigmoid(zg[1]);
            float so = fsigmoid(zg[2]);
            float tg = ftanh_(zg[3]);
            c = fmaf(sf, c, si * tg);
            float h = so * ftanh_(c);

            // publish: write-through to coherence point, then drain
            __hip_atomic_store(&hs[(((size_t)tf * E4_ + (rj >> 2)) * B_ + b) * 4 + (rj & 3)],
                               h, __ATOMIC_RELAXED, __HIP_MEMORY_SCOPE_AGENT);
            asm volatile("s_waitcnt vmcnt(0)" ::: "memory");
        }

        __syncthreads();   // publish drained by all publisher waves; zp reusable
        if (tid == 0)
            __hip_atomic_fetch_add(&mycnt[(size_t)t * NBANK_ * 16 + mybank], 1u,
                                   __ATOMIC_RELAXED, __HIP_MEMORY_SCOPE_AGENT);
    }
}

// out[t][b][e] = hsF[t][e4][b][.] + hsB[t][e4][b][.]
__global__ __launch_bounds__(256) void t4_to_row_k(
    const float* __restrict__ hsF, const float* __restrict__ hsB,
    float* __restrict__ out)
{
    int i  = blockIdx.x * 256 + threadIdx.x;   // 2,097,152 float4 units
    int e4 = i & (E4_ - 1);
    int b  = (i >> 7) & 63;
    int t  = i >> 13;
    size_t idx = ((size_t)t * E4_ + e4) * B_ + b;
    float4 u = ((const float4*)hsF)[idx];
    float4 v = ((const float4*)hsB)[idx];
    *(float4*)&out[((size_t)(t * B_ + b)) * E_ + e4 * 4] =
        make_float4(u.x + v.x, u.y + v.y, u.z + v.z, u.w + v.w);
}

// tail [b][j] = h_fwd(tf=255) + h_bwd(tf=0)
__global__ __launch_bounds__(256) void tail_k(
    const float* __restrict__ hsF, const float* __restrict__ hsB,
    float* __restrict__ out2)
{
    int i = blockIdx.x * 256 + threadIdx.x;   // 32768
    int b = i >> 9, j = i & 511;
    size_t f = (((size_t)255 * E4_ + (j >> 2)) * B_ + b) * 4 + (j & 3);
    size_t g = (((size_t)0   * E4_ + (j >> 2)) * B_ + b) * 4 + (j & 3);
    out2[i] = hsF[f] + hsB[g];
}

// ---------------------------------------------------------------------------
// Workspace (floats):
//   pre : 33,554,432   hsF : 8,388,608   hsB : 8,388,608
//   cnt : 2*256*16*16 u32 = 512 KB
// total ~192.5 MiB
// ---------------------------------------------------------------------------
extern "C" void kernel_launch(void* const* d_in, const int* in_sizes, int n_in,
                              void* d_out, int out_size, void* d_ws, size_t ws_size,
                              hipStream_t stream) {
    const float* x    = (const float*)d_in[0];
    const float* Wi   = (const float*)d_in[1];
    const float* Wh   = (const float*)d_in[2];
    const float* bias = (const float*)d_in[3];
    float* out = (float*)d_out;

    float* ws  = (float*)d_ws;
    float* pre = ws;
    float* hsF = pre + (size_t)S_ * G4_ * B_;
    float* hsB = hsF + (size_t)S_ * B_ * H_;
    unsigned* cnt = (unsigned*)(hsB + (size_t)S_ * B_ * H_);

    for (int l = 0; l < NL_; ++l) {
        const float* wi_l = Wi + (size_t)l * G4_ * E_;
        const float* wh_l = Wh + (size_t)l * G4_ * H_;
        const float* b_l  = bias + (size_t)l * G4_;
        if (l == 0) pre_gemm_k<0><<<2048, 256, 0, stream>>>(x,   x,   wi_l, b_l, pre);
        else        pre_gemm_k<1><<<2048, 256, 0, stream>>>(hsF, hsB, wi_l, b_l, pre);
        hipMemsetAsync(cnt, 0, (size_t)2 * S_ * NBANK_ * 16 * sizeof(unsigned), stream);
        lstm_persist_k<<<512, 512, 0, stream>>>(pre, wh_l, hsF, hsB, cnt);
    }
    t4_to_row_k<<<8192, 256, 0, stream>>>(hsF, hsB, out);
    tail_k<<<128, 256, 0, stream>>>(hsF, hsB, out + (size_t)S_ * B_ * H_);
}

// Round 7
// 12715.768 us; speedup vs baseline: 4.1287x; 1.2679x over previous
//
#include <hip/hip_runtime.h>
#include <math.h>

#define S_  256
#define B_  64
#define E_  512
#define H_  512
#define G4_ 2048   // 4*H
#define NL_ 4
#define E4_ 128    // H/4

typedef __attribute__((ext_vector_type(8))) short bf16x8;
typedef __attribute__((ext_vector_type(4))) float f32x4;

__device__ __forceinline__ float fsigmoid(float x) {
    return 1.0f / (1.0f + __expf(-x));
}
__device__ __forceinline__ float ftanh_(float x) {
    x = fminf(fmaxf(x, -15.0f), 15.0f);
    float e = __expf(2.0f * x);
    return (e - 1.0f) / (e + 1.0f);
}
__device__ __forceinline__ ushort f2bf(float x) {   // RNE float->bf16
    unsigned u = __float_as_uint(x);
    return (ushort)((u + 0x7FFFu + ((u >> 16) & 1u)) >> 16);
}
__device__ __forceinline__ float bf2f(ushort u) {
    return __uint_as_float((unsigned)u << 16);
}

// ---------------------------------------------------------------------------
// A-tile loader: T4=0 -> row-major [M][E]; T4=1 -> [t][e4][b][4] dual (hsF+hsB)
// ---------------------------------------------------------------------------
template<int T4>
__device__ __forceinline__ float4 ldA(const float* __restrict__ A,
                                      const float* __restrict__ A2,
                                      int m, int kk) {
    if constexpr (T4) {
        int t = m >> 6, b = m & 63;
        size_t idx = (((size_t)t * E4_ + (kk >> 2)) * B_ + b) * 4;
        float4 u = *(const float4*)&A[idx];
        float4 v = *(const float4*)&A2[idx];
        return make_float4(u.x + v.x, u.y + v.y, u.z + v.z, u.w + v.w);
    } else {
        return *(const float4*)&A[(size_t)m * E_ + kk];
    }
}

// pre[t][g][b] = sum_k In[t*64+b][k] * Wi[g][k] + bias[g]
#define BM_ 128
#define BN_ 128
#define BK_ 16

template<int T4>
__global__ __launch_bounds__(256) void pre_gemm_k(
    const float* __restrict__ In,
    const float* __restrict__ In2,
    const float* __restrict__ Wi,
    const float* __restrict__ bias,
    float* __restrict__ pre)
{
    __shared__ float As[BK_][BM_ + 4];
    __shared__ float Bs[BK_][BN_ + 4];

    const int tid = threadIdx.x;
    const int bx  = blockIdx.x;          // 0..2047
    const int m0  = (bx >> 4) * BM_;
    const int n0  = (bx & 15) * BN_;
    const int tx  = tid & 15;
    const int ty  = tid >> 4;
    const int lr  = tid >> 2;            // 0..63
    const int lc  = (tid & 3) << 2;      // 0,4,8,12

    float acc[8][8];
#pragma unroll
    for (int i = 0; i < 8; ++i)
#pragma unroll
        for (int j = 0; j < 8; ++j) acc[i][j] = 0.0f;

    for (int k0 = 0; k0 < E_; k0 += BK_) {
        float4 a0 = ldA<T4>(In, In2, m0 + lr,      k0 + lc);
        float4 a1 = ldA<T4>(In, In2, m0 + lr + 64, k0 + lc);
        float4 b0 = *(const float4*)&Wi[(size_t)(n0 + lr) * E_ + k0 + lc];
        float4 b1 = *(const float4*)&Wi[(size_t)(n0 + lr + 64) * E_ + k0 + lc];
        __syncthreads();
        As[lc + 0][lr] = a0.x; As[lc + 1][lr] = a0.y; As[lc + 2][lr] = a0.z; As[lc + 3][lr] = a0.w;
        As[lc + 0][lr + 64] = a1.x; As[lc + 1][lr + 64] = a1.y; As[lc + 2][lr + 64] = a1.z; As[lc + 3][lr + 64] = a1.w;
        Bs[lc + 0][lr] = b0.x; Bs[lc + 1][lr] = b0.y; Bs[lc + 2][lr] = b0.z; Bs[lc + 3][lr] = b0.w;
        Bs[lc + 0][lr + 64] = b1.x; Bs[lc + 1][lr + 64] = b1.y; Bs[lc + 2][lr + 64] = b1.z; Bs[lc + 3][lr + 64] = b1.w;
        __syncthreads();
#pragma unroll
        for (int kk = 0; kk < BK_; ++kk) {
            float4 av0 = *(const float4*)&As[kk][ty * 8];
            float4 av1 = *(const float4*)&As[kk][ty * 8 + 4];
            float4 bv0 = *(const float4*)&Bs[kk][tx * 8];
            float4 bv1 = *(const float4*)&Bs[kk][tx * 8 + 4];
            float a[8] = {av0.x, av0.y, av0.z, av0.w, av1.x, av1.y, av1.z, av1.w};
            float b[8] = {bv0.x, bv0.y, bv0.z, bv0.w, bv1.x, bv1.y, bv1.z, bv1.w};
#pragma unroll
            for (int i = 0; i < 8; ++i)
#pragma unroll
                for (int j = 0; j < 8; ++j)
                    acc[i][j] = fmaf(a[i], b[j], acc[i][j]);
        }
    }

#pragma unroll
    for (int i = 0; i < 8; ++i) {
        int m  = m0 + ty * 8 + i;
        int tt = m >> 6;
        int bb = m & 63;
#pragma unroll
        for (int j = 0; j < 8; ++j) {
            int n = n0 + tx * 8 + j;
            pre[((size_t)tt * G4_ + n) * B_ + bb] = acc[i][j] + bias[n];
        }
    }
}

// ---------------------------------------------------------------------------
// Wh (fp32 [2048][512]) -> hi/lo bf16 pair in MFMA-A-fragment order:
//   idx[wgin][w][ks][lane][e]; lane l: r=l&15 -> (g=r&3, j=wgin*16+w*4+(r>>2)),
//   k = ks*32 + (l>>4)*8 + e.   x ~= hi + lo, lo = bf16(x - hi).
// ---------------------------------------------------------------------------
__global__ __launch_bounds__(256) void whb_k(
    const float* __restrict__ Wh,
    ushort* __restrict__ WhH, ushort* __restrict__ WhL)
{
    int i = blockIdx.x * 256 + threadIdx.x;       // 1,048,576
    int e = i & 7, l = (i >> 3) & 63, ks = (i >> 9) & 15;
    int w = (i >> 13) & 3, wgin = i >> 15;
    int r = l & 15, g = r & 3, j = wgin * 16 + w * 4 + (r >> 2);
    int k = ks * 32 + ((l >> 4) << 3) + e;
    float x = Wh[(size_t)(g * H_ + j) * H_ + k];
    ushort hi = f2bf(x);
    WhH[i] = hi;
    WhL[i] = f2bf(x - bf2f(hi));
}

// ---------------------------------------------------------------------------
// Persistent recurrence v5: batch-split chains + DOUBLE-bf16 MFMA.
// Structure identical to R6 (verified): 8 groups x 32 WGs, 16 chains/group,
// WG owns 16 j; wave w -> rows r=(jloc<<2)|g, lane-local gates/c/h.
// Precision fix: Wh and h both split hi/lo bf16; z = Ah*Bh + Ah*Bl + Al*Bh
// (48 chained mfma_f32_16x16x32_bf16, all products exact in fp32 accum).
// Sync: 32-WG relaxed-agent counter + write-through first-touch h publish.
// ---------------------------------------------------------------------------
__global__ __launch_bounds__(256) void lstm_persist_k(
    const float* __restrict__ pre,    // [S][G4][B]
    const ushort* __restrict__ WhH,   // frag-ordered bf16 hi
    const ushort* __restrict__ WhL,   // frag-ordered bf16 lo
    float* __restrict__ hsF,          // [S][E4][B][4]
    float* __restrict__ hsB,          // [S][E4][B][4]
    unsigned* __restrict__ cnt)       // [8][S][16], zeroed before launch
{
    __shared__ ushort hS[16384];      // hi: [0,8192) lo: [8192,16384), swizzled

    const int tid  = threadIdx.x;
    const int grp  = blockIdx.x & 7;
    const int wgin = blockIdx.x >> 3;            // 0..31
    const int dir  = grp & 1;
    const int bblk = grp >> 1;
    const int w    = tid >> 6;                   // wave / row-tile
    const int l    = tid & 63;
    const int ch   = l & 15;
    const int jloc = l >> 4;                     // 0..3
    const int j    = wgin * 16 + w * 4 + jloc;
    const int b    = bblk * 16 + ch;
    const int khi8 = (l >> 4) << 3;

    float* hs = dir ? hsB : hsF;
    unsigned* mycnt = &cnt[((size_t)grp * S_) * 16];
    const ushort* wbaseH = WhH + ((size_t)(wgin * 4 + w) << 13) + (l << 3);
    const ushort* wbaseL = WhL + ((size_t)(wgin * 4 + w) << 13) + (l << 3);
    uint* hSu = (uint*)hS;

    float c = 0.0f;

    for (int t = 0; t < S_; ++t) {
        const int tf = dir ? (S_ - 1 - t) : t;

        // own (j,ch) pre values for all 4 gates -> MFMA C-in (issued pre-poll)
        f32x4 acc;
#pragma unroll
        for (int g = 0; g < 4; ++g)
            acc[g] = pre[((size_t)tf * G4_ + g * H_ + j) * B_ + b];

        if (t > 0) {
            // group barrier: poll (relaxed agent, no cache maintenance)
            unsigned guard = 0;
            while (__hip_atomic_load(&mycnt[(size_t)(t - 1) * 16], __ATOMIC_RELAXED,
                                     __HIP_MEMORY_SCOPE_AGENT) < 32u) {
                if (++guard > (1u << 16)) break;   // fail visibly, don't hang
            }

            // stage h(prev) -> hS hi/lo bf16 (swizzled), first-touch reads
            const int tfp = dir ? (tf + 1) : (tf - 1);
            const float4* src = (const float4*)hs + (size_t)tfp * (E4_ * B_);
#pragma unroll
            for (int i = 0; i < 8; ++i) {
                int q  = tid + (i << 8);
                int cc = q & 15;
                int e4 = q >> 4;                  // 0..127
                float4 v = src[(size_t)e4 * B_ + bblk * 16 + cc];
                ushort hx = f2bf(v.x), hy = f2bf(v.y), hz = f2bf(v.z), hw4 = f2bf(v.w);
                uint2 uh, ul;
                uh.x = (uint)hx | ((uint)hy << 16);
                uh.y = (uint)hz | ((uint)hw4 << 16);
                ul.x = (uint)f2bf(v.x - bf2f(hx)) | ((uint)f2bf(v.y - bf2f(hy)) << 16);
                ul.y = (uint)f2bf(v.z - bf2f(hz)) | ((uint)f2bf(v.w - bf2f(hw4)) << 16);
                int hw = ((cc << 9) + (e4 << 2)) ^ ((cc & 7) << 3);
                *(uint2*)&hSu[hw >> 1] = uh;
                *(uint2*)&hSu[4096 + (hw >> 1)] = ul;
            }
            __syncthreads();

            // 48 chained MFMAs over K=512 (hi*hi + hi*lo + lo*hi)
#pragma unroll
            for (int ks = 0; ks < 16; ++ks) {
                int hw = ((ch << 9) + ks * 32 + khi8) ^ ((ch & 7) << 3);
                bf16x8 bh = *(const bf16x8*)&hS[hw];
                bf16x8 bl = *(const bf16x8*)&hS[8192 + hw];
                bf16x8 ah = *(const bf16x8*)(wbaseH + (ks << 9));
                bf16x8 al = *(const bf16x8*)(wbaseL + (ks << 9));
                acc = __builtin_amdgcn_mfma_f32_16x16x32_bf16(ah, bh, acc, 0, 0, 0);
                acc = __builtin_amdgcn_mfma_f32_16x16x32_bf16(ah, bl, acc, 0, 0, 0);
                acc = __builtin_amdgcn_mfma_f32_16x16x32_bf16(al, bh, acc, 0, 0, 0);
            }
        }

        // gates (order i,f,o,g), fully lane-local
        float si = fsigmoid(acc[0]);
        float sf = fsigmoid(acc[1]);
        float so = fsigmoid(acc[2]);
        float tg = ftanh_(acc[3]);
        c = fmaf(sf, c, si * tg);
        float h = so * ftanh_(c);

        // publish h (write-through to coherence point), drain, signal
        __hip_atomic_store(&hs[(((size_t)tf * E4_ + (j >> 2)) * B_ + b) * 4 + (j & 3)],
                           h, __ATOMIC_RELAXED, __HIP_MEMORY_SCOPE_AGENT);
        asm volatile("s_waitcnt vmcnt(0)" ::: "memory");
        __syncthreads();
        if (tid == 0)
            __hip_atomic_fetch_add(&mycnt[(size_t)t * 16], 1u,
                                   __ATOMIC_RELAXED, __HIP_MEMORY_SCOPE_AGENT);
    }
}

// out[t][b][e] = hsF[t][e4][b][.] + hsB[t][e4][b][.]
__global__ __launch_bounds__(256) void t4_to_row_k(
    const float* __restrict__ hsF, const float* __restrict__ hsB,
    float* __restrict__ out)
{
    int i  = blockIdx.x * 256 + threadIdx.x;   // 2,097,152 float4 units
    int e4 = i & (E4_ - 1);
    int b  = (i >> 7) & 63;
    int t  = i >> 13;
    size_t idx = ((size_t)t * E4_ + e4) * B_ + b;
    float4 u = ((const float4*)hsF)[idx];
    float4 v = ((const float4*)hsB)[idx];
    *(float4*)&out[((size_t)(t * B_ + b)) * E_ + e4 * 4] =
        make_float4(u.x + v.x, u.y + v.y, u.z + v.z, u.w + v.w);
}

// tail [b][j] = h_fwd(tf=255) + h_bwd(tf=0)
__global__ __launch_bounds__(256) void tail_k(
    const float* __restrict__ hsF, const float* __restrict__ hsB,
    float* __restrict__ out2)
{
    int i = blockIdx.x * 256 + threadIdx.x;   // 32768
    int b = i >> 9, j = i & 511;
    size_t f = (((size_t)255 * E4_ + (j >> 2)) * B_ + b) * 4 + (j & 3);
    size_t g = (((size_t)0   * E4_ + (j >> 2)) * B_ + b) * 4 + (j & 3);
    out2[i] = hsF[f] + hsB[g];
}

// ---------------------------------------------------------------------------
// Workspace (float units):
//   pre : 33,554,432   hsF : 8,388,608   hsB : 8,388,608
//   cnt : 8*256*16 u32 (128 KB)
//   WhH : 1,048,576 bf16 (2 MB)   WhL : 1,048,576 bf16 (2 MB)
// total ~196.2 MiB
// ---------------------------------------------------------------------------
extern "C" void kernel_launch(void* const* d_in, const int* in_sizes, int n_in,
                              void* d_out, int out_size, void* d_ws, size_t ws_size,
                              hipStream_t stream) {
    const float* x    = (const float*)d_in[0];
    const float* Wi   = (const float*)d_in[1];
    const float* Wh   = (const float*)d_in[2];
    const float* bias = (const float*)d_in[3];
    float* out = (float*)d_out;

    float* ws  = (float*)d_ws;
    float* pre = ws;
    float* hsF = pre + (size_t)S_ * G4_ * B_;
    float* hsB = hsF + (size_t)S_ * B_ * H_;
    unsigned* cnt = (unsigned*)(hsB + (size_t)S_ * B_ * H_);
    ushort* WhH = (ushort*)(cnt + (size_t)8 * S_ * 16);
    ushort* WhL = WhH + (size_t)1024 * 1024;

    for (int l = 0; l < NL_; ++l) {
        const float* wi_l = Wi + (size_t)l * G4_ * E_;
        const float* wh_l = Wh + (size_t)l * G4_ * H_;
        const float* b_l  = bias + (size_t)l * G4_;
        if (l == 0) pre_gemm_k<0><<<2048, 256, 0, stream>>>(x,   x,   wi_l, b_l, pre);
        else        pre_gemm_k<1><<<2048, 256, 0, stream>>>(hsF, hsB, wi_l, b_l, pre);
        whb_k<<<4096, 256, 0, stream>>>(wh_l, WhH, WhL);
        hipMemsetAsync(cnt, 0, (size_t)8 * S_ * 16 * sizeof(unsigned), stream);
        lstm_persist_k<<<256, 256, 0, stream>>>(pre, WhH, WhL, hsF, hsB, cnt);
    }
    t4_to_row_k<<<8192, 256, 0, stream>>>(hsF, hsB, out);
    tail_k<<<128, 256, 0, stream>>>(hsF, hsB, out + (size_t)S_ * B_ * H_);
}

// Round 8
// 5149.735 us; speedup vs baseline: 10.1946x; 2.4692x over previous
//
#include <hip/hip_runtime.h>
#include <math.h>

#define S_  256
#define B_  64
#define E_  512
#define H_  512
#define G4_ 2048   // 4*H
#define NL_ 4
#define E4_ 128    // H/4

typedef __attribute__((ext_vector_type(8))) short bf16x8;
typedef __attribute__((ext_vector_type(4))) float f32x4;

__device__ __forceinline__ float fsigmoid(float x) {
    return 1.0f / (1.0f + __expf(-x));
}
__device__ __forceinline__ float ftanh_(float x) {
    x = fminf(fmaxf(x, -15.0f), 15.0f);
    float e = __expf(2.0f * x);
    return (e - 1.0f) / (e + 1.0f);
}
__device__ __forceinline__ ushort f2bf(float x) {   // RNE float->bf16
    unsigned u = __float_as_uint(x);
    return (ushort)((u + 0x7FFFu + ((u >> 16) & 1u)) >> 16);
}
__device__ __forceinline__ float bf2f(ushort u) {
    return __uint_as_float((unsigned)u << 16);
}

// ---------------------------------------------------------------------------
// A-tile loader: T4=0 -> row-major [M][E]; T4=1 -> [t][e4][b][4] dual (hsF+hsB)
// ---------------------------------------------------------------------------
template<int T4>
__device__ __forceinline__ float4 ldA(const float* __restrict__ A,
                                      const float* __restrict__ A2,
                                      int m, int kk) {
    if constexpr (T4) {
        int t = m >> 6, b = m & 63;
        size_t idx = (((size_t)t * E4_ + (kk >> 2)) * B_ + b) * 4;
        float4 u = *(const float4*)&A[idx];
        float4 v = *(const float4*)&A2[idx];
        return make_float4(u.x + v.x, u.y + v.y, u.z + v.z, u.w + v.w);
    } else {
        return *(const float4*)&A[(size_t)m * E_ + kk];
    }
}

// pre[t][g][b] = sum_k In[t*64+b][k] * Wi[g][k] + bias[g]
#define BM_ 128
#define BN_ 128
#define BK_ 16

template<int T4>
__global__ __launch_bounds__(256) void pre_gemm_k(
    const float* __restrict__ In,
    const float* __restrict__ In2,
    const float* __restrict__ Wi,
    const float* __restrict__ bias,
    float* __restrict__ pre)
{
    __shared__ float As[BK_][BM_ + 4];
    __shared__ float Bs[BK_][BN_ + 4];

    const int tid = threadIdx.x;
    const int bx  = blockIdx.x;          // 0..2047
    const int m0  = (bx >> 4) * BM_;
    const int n0  = (bx & 15) * BN_;
    const int tx  = tid & 15;
    const int ty  = tid >> 4;
    const int lr  = tid >> 2;            // 0..63
    const int lc  = (tid & 3) << 2;      // 0,4,8,12

    float acc[8][8];
#pragma unroll
    for (int i = 0; i < 8; ++i)
#pragma unroll
        for (int j = 0; j < 8; ++j) acc[i][j] = 0.0f;

    for (int k0 = 0; k0 < E_; k0 += BK_) {
        float4 a0 = ldA<T4>(In, In2, m0 + lr,      k0 + lc);
        float4 a1 = ldA<T4>(In, In2, m0 + lr + 64, k0 + lc);
        float4 b0 = *(const float4*)&Wi[(size_t)(n0 + lr) * E_ + k0 + lc];
        float4 b1 = *(const float4*)&Wi[(size_t)(n0 + lr + 64) * E_ + k0 + lc];
        __syncthreads();
        As[lc + 0][lr] = a0.x; As[lc + 1][lr] = a0.y; As[lc + 2][lr] = a0.z; As[lc + 3][lr] = a0.w;
        As[lc + 0][lr + 64] = a1.x; As[lc + 1][lr + 64] = a1.y; As[lc + 2][lr + 64] = a1.z; As[lc + 3][lr + 64] = a1.w;
        Bs[lc + 0][lr] = b0.x; Bs[lc + 1][lr] = b0.y; Bs[lc + 2][lr] = b0.z; Bs[lc + 3][lr] = b0.w;
        Bs[lc + 0][lr + 64] = b1.x; Bs[lc + 1][lr + 64] = b1.y; Bs[lc + 2][lr + 64] = b1.z; Bs[lc + 3][lr + 64] = b1.w;
        __syncthreads();
#pragma unroll
        for (int kk = 0; kk < BK_; ++kk) {
            float4 av0 = *(const float4*)&As[kk][ty * 8];
            float4 av1 = *(const float4*)&As[kk][ty * 8 + 4];
            float4 bv0 = *(const float4*)&Bs[kk][tx * 8];
            float4 bv1 = *(const float4*)&Bs[kk][tx * 8 + 4];
            float a[8] = {av0.x, av0.y, av0.z, av0.w, av1.x, av1.y, av1.z, av1.w};
            float b[8] = {bv0.x, bv0.y, bv0.z, bv0.w, bv1.x, bv1.y, bv1.z, bv1.w};
#pragma unroll
            for (int i = 0; i < 8; ++i)
#pragma unroll
                for (int j = 0; j < 8; ++j)
                    acc[i][j] = fmaf(a[i], b[j], acc[i][j]);
        }
    }

#pragma unroll
    for (int i = 0; i < 8; ++i) {
        int m  = m0 + ty * 8 + i;
        int tt = m >> 6;
        int bb = m & 63;
#pragma unroll
        for (int j = 0; j < 8; ++j) {
            int n = n0 + tx * 8 + j;
            pre[((size_t)tt * G4_ + n) * B_ + bb] = acc[i][j] + bias[n];
        }
    }
}

// ---------------------------------------------------------------------------
// Wh (fp32 [2048][512]) -> hi/lo bf16 pair in MFMA-A-fragment order:
//   idx[wgin][w][ks][lane][e]; lane l: r=l&15 -> (g=r&3, j=wgin*16+w*4+(r>>2)),
//   k = ks*32 + (l>>4)*8 + e.   x ~= hi + lo, lo = bf16(x - hi).
// ---------------------------------------------------------------------------
__global__ __launch_bounds__(256) void whb_k(
    const float* __restrict__ Wh,
    ushort* __restrict__ WhH, ushort* __restrict__ WhL)
{
    int i = blockIdx.x * 256 + threadIdx.x;       // 1,048,576
    int e = i & 7, l = (i >> 3) & 63, ks = (i >> 9) & 15;
    int w = (i >> 13) & 3, wgin = i >> 15;
    int r = l & 15, g = r & 3, j = wgin * 16 + w * 4 + (r >> 2);
    int k = ks * 32 + ((l >> 4) << 3) + e;
    float x = Wh[(size_t)(g * H_ + j) * H_ + k];
    ushort hi = f2bf(x);
    WhH[i] = hi;
    WhL[i] = f2bf(x - bf2f(hi));
}

// ---------------------------------------------------------------------------
// Persistent recurrence v6: weights-in-registers + conflict-free frag LDS.
// Mapping swap vs R7: grp = bid>>5 (sync domain), wgin = bid&31. XCD = bid%8
// = wgin&7 -> each XCD hosts 4 wgin slices x 8 groups sharing them: unique
// weights/XCD = 512 KB (L2-resident for the one-time preload).
// Each wave preloads its ENTIRE weight slice (16 ks x hi/lo bf16x8 = 128
// VGPRs, 32 KB) before the t-loop -> zero weight traffic per step.
// LDS: h staged in MFMA-B-frag order hS[ks][lane][e] (hi @0, lo @8192):
//   read  = ds_read_b128 at base + lane*16 (conflict-free)
//   write = 64 distinct 8B slots covering contiguous 512B (bank floor).
// 3 independent MFMA accumulators (hi*hi C-in=pre, hi*lo, lo*hi) pipeline.
// Sync/publish protocol identical to R5-R7 (proven).
// ---------------------------------------------------------------------------
__global__ __launch_bounds__(256, 1) void lstm_persist_k(
    const float* __restrict__ pre,    // [S][G4][B]
    const ushort* __restrict__ WhH,   // frag-ordered bf16 hi
    const ushort* __restrict__ WhL,   // frag-ordered bf16 lo
    float* __restrict__ hsF,          // [S][E4][B][4]
    float* __restrict__ hsB,          // [S][E4][B][4]
    unsigned* __restrict__ cnt)       // [8][S][16], zeroed before launch
{
    __shared__ ushort hS[16384];      // hi: [0,8192) lo: [8192,16384) frag order

    const int tid  = threadIdx.x;
    const int grp  = blockIdx.x >> 5;            // 0..7 sync domain
    const int wgin = blockIdx.x & 31;            // 0..31 j-slice (XCD = wgin&7)
    const int dir  = grp & 1;
    const int bblk = grp >> 1;
    const int w    = tid >> 6;                   // wave / row-tile
    const int l    = tid & 63;
    const int ch   = l & 15;
    const int jloc = l >> 4;                     // 0..3
    const int j    = wgin * 16 + w * 4 + jloc;
    const int b    = bblk * 16 + ch;

    float* hs = dir ? hsB : hsF;
    unsigned* mycnt = &cnt[((size_t)grp * S_) * 16];
    const ushort* wbaseH = WhH + ((size_t)(wgin * 4 + w) << 13) + (l << 3);
    const ushort* wbaseL = WhL + ((size_t)(wgin * 4 + w) << 13) + (l << 3);
    uint* hSu = (uint*)hS;

    // preload this wave's full weight slice into registers (128 VGPRs)
    bf16x8 wH[16], wL[16];
#pragma unroll
    for (int ks = 0; ks < 16; ++ks) {
        wH[ks] = *(const bf16x8*)(wbaseH + (ks << 9));
        wL[ks] = *(const bf16x8*)(wbaseL + (ks << 9));
    }

    float c = 0.0f;

    for (int t = 0; t < S_; ++t) {
        const int tf = dir ? (S_ - 1 - t) : t;

        // own (j,ch) pre values for all 4 gates -> MFMA C-in (issued pre-poll)
        f32x4 acc;
#pragma unroll
        for (int g = 0; g < 4; ++g)
            acc[g] = pre[((size_t)tf * G4_ + g * H_ + j) * B_ + b];

        if (t > 0) {
            // group barrier: poll (relaxed agent, no cache maintenance)
            unsigned guard = 0;
            while (__hip_atomic_load(&mycnt[(size_t)(t - 1) * 16], __ATOMIC_RELAXED,
                                     __HIP_MEMORY_SCOPE_AGENT) < 32u) {
                if (++guard > (1u << 16)) break;   // fail visibly, don't hang
            }

            // stage h(prev) -> hS hi/lo bf16 in frag order, first-touch reads
            const int tfp = dir ? (tf + 1) : (tf - 1);
            const float4* src = (const float4*)hs + (size_t)tfp * (E4_ * B_);
#pragma unroll
            for (int i = 0; i < 8; ++i) {
                int q  = tid + (i << 8);
                int cc = q & 15;
                int e4 = q >> 4;                  // 0..127  (k = 4*e4 + 0..3)
                float4 v = src[(size_t)e4 * B_ + bblk * 16 + cc];
                ushort hx = f2bf(v.x), hy = f2bf(v.y), hz = f2bf(v.z), hw4 = f2bf(v.w);
                uint2 uh, ul;
                uh.x = (uint)hx | ((uint)hy << 16);
                uh.y = (uint)hz | ((uint)hw4 << 16);
                ul.x = (uint)f2bf(v.x - bf2f(hx)) | ((uint)f2bf(v.y - bf2f(hy)) << 16);
                ul.y = (uint)f2bf(v.z - bf2f(hz)) | ((uint)f2bf(v.w - bf2f(hw4)) << 16);
                // frag slot: ks=e4>>3, lane=((e4>>1)&3)*16+cc, e=4*(e4&1)+kk
                int idx = ((e4 >> 3) << 9) + (((((e4 >> 1) & 3) << 4) + cc) << 3)
                        + ((e4 & 1) << 2);        // ushort index, %4==0
                *(uint2*)&hSu[idx >> 1] = uh;
                *(uint2*)&hSu[4096 + (idx >> 1)] = ul;
            }
            __syncthreads();

            // 48 MFMAs over K=512, 3 independent chains
            f32x4 aB = {0.f, 0.f, 0.f, 0.f}, aC = {0.f, 0.f, 0.f, 0.f};
#pragma unroll
            for (int ks = 0; ks < 16; ++ks) {
                int ridx = (ks << 9) + (l << 3);
                bf16x8 bh = *(const bf16x8*)&hS[ridx];
                bf16x8 bl = *(const bf16x8*)&hS[8192 + ridx];
                acc = __builtin_amdgcn_mfma_f32_16x16x32_bf16(wH[ks], bh, acc, 0, 0, 0);
                aB  = __builtin_amdgcn_mfma_f32_16x16x32_bf16(wH[ks], bl, aB, 0, 0, 0);
                aC  = __builtin_amdgcn_mfma_f32_16x16x32_bf16(wL[ks], bh, aC, 0, 0, 0);
            }
#pragma unroll
            for (int g = 0; g < 4; ++g) acc[g] += aB[g] + aC[g];
        }

        // gates (order i,f,o,g), fully lane-local
        float si = fsigmoid(acc[0]);
        float sf = fsigmoid(acc[1]);
        float so = fsigmoid(acc[2]);
        float tg = ftanh_(acc[3]);
        c = fmaf(sf, c, si * tg);
        float h = so * ftanh_(c);

        // publish h (write-through to coherence point), drain, signal
        __hip_atomic_store(&hs[(((size_t)tf * E4_ + (j >> 2)) * B_ + b) * 4 + (j & 3)],
                           h, __ATOMIC_RELAXED, __HIP_MEMORY_SCOPE_AGENT);
        asm volatile("s_waitcnt vmcnt(0)" ::: "memory");
        __syncthreads();
        if (tid == 0)
            __hip_atomic_fetch_add(&mycnt[(size_t)t * 16], 1u,
                                   __ATOMIC_RELAXED, __HIP_MEMORY_SCOPE_AGENT);
    }
}

// out[t][b][e] = hsF[t][e4][b][.] + hsB[t][e4][b][.]
__global__ __launch_bounds__(256) void t4_to_row_k(
    const float* __restrict__ hsF, const float* __restrict__ hsB,
    float* __restrict__ out)
{
    int i  = blockIdx.x * 256 + threadIdx.x;   // 2,097,152 float4 units
    int e4 = i & (E4_ - 1);
    int b  = (i >> 7) & 63;
    int t  = i >> 13;
    size_t idx = ((size_t)t * E4_ + e4) * B_ + b;
    float4 u = ((const float4*)hsF)[idx];
    float4 v = ((const float4*)hsB)[idx];
    *(float4*)&out[((size_t)(t * B_ + b)) * E_ + e4 * 4] =
        make_float4(u.x + v.x, u.y + v.y, u.z + v.z, u.w + v.w);
}

// tail [b][j] = h_fwd(tf=255) + h_bwd(tf=0)
__global__ __launch_bounds__(256) void tail_k(
    const float* __restrict__ hsF, const float* __restrict__ hsB,
    float* __restrict__ out2)
{
    int i = blockIdx.x * 256 + threadIdx.x;   // 32768
    int b = i >> 9, j = i & 511;
    size_t f = (((size_t)255 * E4_ + (j >> 2)) * B_ + b) * 4 + (j & 3);
    size_t g = (((size_t)0   * E4_ + (j >> 2)) * B_ + b) * 4 + (j & 3);
    out2[i] = hsF[f] + hsB[g];
}

// ---------------------------------------------------------------------------
// Workspace (float units):
//   pre : 33,554,432   hsF : 8,388,608   hsB : 8,388,608
//   cnt : 8*256*16 u32 (128 KB)
//   WhH : 1,048,576 bf16 (2 MB)   WhL : 1,048,576 bf16 (2 MB)
// total ~196.2 MiB
// ---------------------------------------------------------------------------
extern "C" void kernel_launch(void* const* d_in, const int* in_sizes, int n_in,
                              void* d_out, int out_size, void* d_ws, size_t ws_size,
                              hipStream_t stream) {
    const float* x    = (const float*)d_in[0];
    const float* Wi   = (const float*)d_in[1];
    const float* Wh   = (const float*)d_in[2];
    const float* bias = (const float*)d_in[3];
    float* out = (float*)d_out;

    float* ws  = (float*)d_ws;
    float* pre = ws;
    float* hsF = pre + (size_t)S_ * G4_ * B_;
    float* hsB = hsF + (size_t)S_ * B_ * H_;
    unsigned* cnt = (unsigned*)(hsB + (size_t)S_ * B_ * H_);
    ushort* WhH = (ushort*)(cnt + (size_t)8 * S_ * 16);
    ushort* WhL = WhH + (size_t)1024 * 1024;

    for (int l = 0; l < NL_; ++l) {
        const float* wi_l = Wi + (size_t)l * G4_ * E_;
        const float* wh_l = Wh + (size_t)l * G4_ * H_;
        const float* b_l  = bias + (size_t)l * G4_;
        if (l == 0) pre_gemm_k<0><<<2048, 256, 0, stream>>>(x,   x,   wi_l, b_l, pre);
        else        pre_gemm_k<1><<<2048, 256, 0, stream>>>(hsF, hsB, wi_l, b_l, pre);
        whb_k<<<4096, 256, 0, stream>>>(wh_l, WhH, WhL);
        hipMemsetAsync(cnt, 0, (size_t)8 * S_ * 16 * sizeof(unsigned), stream);
        lstm_persist_k<<<256, 256, 0, stream>>>(pre, WhH, WhL, hsF, hsB, cnt);
    }
    t4_to_row_k<<<8192, 256, 0, stream>>>(hsF, hsB, out);
    tail_k<<<128, 256, 0, stream>>>(hsF, hsB, out + (size_t)S_ * B_ * H_);
}